// Round 1
// baseline (1081.852 us; speedup 1.0000x reference)
//
#include <hip/hip_runtime.h>

#define BROWS 16384
#define DIN   4096
#define NOUT  4096
#define EPSV  1e-5f

typedef __attribute__((ext_vector_type(8))) short short8;
typedef __attribute__((ext_vector_type(4))) float f32x4;

__device__ __forceinline__ unsigned short f32_to_bf16(float f) {
    union { float f; unsigned u; } v;
    v.f = f;
    unsigned r = (v.u + 0x7fffu + ((v.u >> 16) & 1u)) >> 16;  // RNE
    return (unsigned short)r;
}

// ---------------- Kernel 1: row L2-normalize + cast to bf16 ----------------
__global__ __launch_bounds__(256) void normalize_cast_kernel(
    const float* __restrict__ x, unsigned short* __restrict__ A) {
    const int row = blockIdx.x;
    const int tid = threadIdx.x;
    const float4* xr = (const float4*)(x + (size_t)row * DIN);
    float4 v[4];
    float ss = 0.f;
#pragma unroll
    for (int i = 0; i < 4; ++i) {
        v[i] = xr[tid + i * 256];
        ss += v[i].x * v[i].x + v[i].y * v[i].y + v[i].z * v[i].z + v[i].w * v[i].w;
    }
#pragma unroll
    for (int o = 32; o > 0; o >>= 1) ss += __shfl_down(ss, o);
    __shared__ float red[4];
    const int wave = tid >> 6, lane = tid & 63;
    if (lane == 0) red[wave] = ss;
    __syncthreads();
    const float inv = 1.f / (sqrtf(red[0] + red[1] + red[2] + red[3]) + EPSV);
    uint2* Ar = (uint2*)(A + (size_t)row * DIN);
#pragma unroll
    for (int i = 0; i < 4; ++i) {
        uint2 p;
        p.x = (unsigned)f32_to_bf16(v[i].x * inv) | ((unsigned)f32_to_bf16(v[i].y * inv) << 16);
        p.y = (unsigned)f32_to_bf16(v[i].z * inv) | ((unsigned)f32_to_bf16(v[i].w * inv) << 16);
        Ar[tid + i * 256] = p;
    }
}

// ---------------- Kernel 2: W[k][n] fp32 -> Wt[n][k] bf16 ----------------
__global__ __launch_bounds__(256) void transpose_cast_kernel(
    const float* __restrict__ W, unsigned short* __restrict__ Wt) {
    __shared__ float tile[32][33];  // +1 pad: no bank conflicts on transposed read
    const int bn = blockIdx.x * 32, bk = blockIdx.y * 32;
    const int t = threadIdx.x;
    const int lk = t >> 3, ln4 = (t & 7) * 4;
    float4 v = *(const float4*)(W + (size_t)(bk + lk) * NOUT + bn + ln4);
    tile[lk][ln4 + 0] = v.x;
    tile[lk][ln4 + 1] = v.y;
    tile[lk][ln4 + 2] = v.z;
    tile[lk][ln4 + 3] = v.w;
    __syncthreads();
    const int ln = t >> 3, lk4 = (t & 7) * 4;
    uint2 p;
    p.x = (unsigned)f32_to_bf16(tile[lk4 + 0][ln]) | ((unsigned)f32_to_bf16(tile[lk4 + 1][ln]) << 16);
    p.y = (unsigned)f32_to_bf16(tile[lk4 + 2][ln]) | ((unsigned)f32_to_bf16(tile[lk4 + 3][ln]) << 16);
    *(uint2*)(Wt + (size_t)(bn + ln) * DIN + bk + lk4) = p;
}

// ---------------- Kernel 3: C = relu(A @ W + b), bf16 MFMA ----------------
// A [M,K] bf16 row-major; Wt [N,K] bf16 (k contiguous); C [M,N] fp32.
// 128x128 block tile, BK=32, 256 threads = 4 waves, each wave 64x64 (4x4 MFMA tiles).

__device__ __forceinline__ void async_copy16(const unsigned short* g, unsigned short* l) {
    __builtin_amdgcn_global_load_lds(
        (const __attribute__((address_space(1))) unsigned int*)g,
        (__attribute__((address_space(3))) unsigned int*)l, 16, 0, 0);
}

__global__ __launch_bounds__(256, 2) void gemm_bias_relu_kernel(
    const unsigned short* __restrict__ A, const unsigned short* __restrict__ Wt,
    const float* __restrict__ bias, float* __restrict__ C) {
    __shared__ __align__(16) unsigned short As[128 * 32];
    __shared__ __align__(16) unsigned short Bs[128 * 32];
    const int tid = threadIdx.x;
    const int wave = tid >> 6, lane = tid & 63;
    const int m0 = blockIdx.y * 128, n0 = blockIdx.x * 128;
    const int wr = (wave >> 1) * 64, wc = (wave & 1) * 64;
    const int lm = lane & 15;             // row-in-tile for A frag / n-in-tile for B frag
    const int lk8 = (lane >> 4) * 8;      // k offset of this lane's 8 bf16

    f32x4 acc[4][4] = {};

    // staging chunk assignment: 512 16B-chunks per matrix, chunk c = row*4 + kchunk
    const int c0 = tid, c1 = tid + 256;
    const unsigned short* gA0 = A + (size_t)(m0 + (c0 >> 2)) * DIN + (c0 & 3) * 8;
    const unsigned short* gA1 = A + (size_t)(m0 + (c1 >> 2)) * DIN + (c1 & 3) * 8;
    const unsigned short* gB0 = Wt + (size_t)(n0 + (c0 >> 2)) * DIN + (c0 & 3) * 8;
    const unsigned short* gB1 = Wt + (size_t)(n0 + (c1 >> 2)) * DIN + (c1 & 3) * 8;
    // wave-uniform LDS bases (hardware scatters lane i to base + i*16)
    unsigned short* lA0 = &As[(c0 & ~63) * 8];
    unsigned short* lA1 = &As[(c1 & ~63) * 8];
    unsigned short* lB0 = &Bs[(c0 & ~63) * 8];
    unsigned short* lB1 = &Bs[(c1 & ~63) * 8];

    for (int k0 = 0; k0 < DIN; k0 += 32) {
        __syncthreads();  // previous iteration's LDS reads complete
        async_copy16(gA0 + k0, lA0);
        async_copy16(gA1 + k0, lA1);
        async_copy16(gB0 + k0, lB0);
        async_copy16(gB1 + k0, lB1);
        __syncthreads();  // staged data visible (vmcnt drained by barrier semantics)

        short8 af[4], bf[4];
#pragma unroll
        for (int i = 0; i < 4; ++i)
            af[i] = *(const short8*)(&As[(wr + i * 16 + lm) * 32 + lk8]);
#pragma unroll
        for (int j = 0; j < 4; ++j)
            bf[j] = *(const short8*)(&Bs[(wc + j * 16 + lm) * 32 + lk8]);
#pragma unroll
        for (int i = 0; i < 4; ++i)
#pragma unroll
            for (int j = 0; j < 4; ++j)
                acc[i][j] = __builtin_amdgcn_mfma_f32_16x16x32_bf16(af[i], bf[j], acc[i][j], 0, 0, 0);
    }

    // epilogue: C/D layout col=lane&15, row=(lane>>4)*4+reg  [m89/m91]
    float bj[4];
#pragma unroll
    for (int j = 0; j < 4; ++j) bj[j] = bias[n0 + wc + j * 16 + lm];
    const int colb = n0 + wc + lm;
    const int rowb = m0 + wr + ((lane >> 4) << 2);
#pragma unroll
    for (int i = 0; i < 4; ++i) {
#pragma unroll
        for (int r = 0; r < 4; ++r) {
            float* cp = C + (size_t)(rowb + i * 16 + r) * NOUT + colb;
#pragma unroll
            for (int j = 0; j < 4; ++j) {
                float v = acc[i][j][r] + bj[j];
                cp[j * 16] = v > 0.f ? v : 0.f;
            }
        }
    }
}

extern "C" void kernel_launch(void* const* d_in, const int* in_sizes, int n_in,
                              void* d_out, int out_size, void* d_ws, size_t ws_size,
                              hipStream_t stream) {
    const float* x = (const float*)d_in[0];
    const float* W = (const float*)d_in[1];
    const float* b = (const float*)d_in[2];
    float* out = (float*)d_out;

    // workspace layout: A_bf16 [16384*4096] (128 MiB) | Wt_bf16 [4096*4096] (32 MiB)
    unsigned short* Abf = (unsigned short*)d_ws;
    unsigned short* Wt = Abf + (size_t)BROWS * DIN;

    normalize_cast_kernel<<<BROWS, 256, 0, stream>>>(x, Abf);
    transpose_cast_kernel<<<dim3(NOUT / 32, DIN / 32), 256, 0, stream>>>(W, Wt);
    gemm_bias_relu_kernel<<<dim3(NOUT / 128, BROWS / 128), 256, 0, stream>>>(Abf, Wt, b, out);
}

// Round 2
// 1069.662 us; speedup vs baseline: 1.0114x; 1.0114x over previous
//
#include <hip/hip_runtime.h>

#define BROWS 16384
#define DIN   4096
#define NOUT  4096
#define EPSV  1e-5f

typedef __attribute__((ext_vector_type(8))) short short8;
typedef __attribute__((ext_vector_type(4))) float f32x4;

__device__ __forceinline__ unsigned short f32_to_bf16(float f) {
    union { float f; unsigned u; } v;
    v.f = f;
    unsigned r = (v.u + 0x7fffu + ((v.u >> 16) & 1u)) >> 16;  // RNE
    return (unsigned short)r;
}

// ---------------- Kernel 1: row L2-normalize + cast to bf16 ----------------
__global__ __launch_bounds__(256) void normalize_cast_kernel(
    const float* __restrict__ x, unsigned short* __restrict__ A) {
    const int row = blockIdx.x;
    const int tid = threadIdx.x;
    const float4* xr = (const float4*)(x + (size_t)row * DIN);
    float4 v[4];
    float ss = 0.f;
#pragma unroll
    for (int i = 0; i < 4; ++i) {
        v[i] = xr[tid + i * 256];
        ss += v[i].x * v[i].x + v[i].y * v[i].y + v[i].z * v[i].z + v[i].w * v[i].w;
    }
#pragma unroll
    for (int o = 32; o > 0; o >>= 1) ss += __shfl_down(ss, o);
    __shared__ float red[4];
    const int wave = tid >> 6, lane = tid & 63;
    if (lane == 0) red[wave] = ss;
    __syncthreads();
    const float inv = 1.f / (sqrtf(red[0] + red[1] + red[2] + red[3]) + EPSV);
    uint2* Ar = (uint2*)(A + (size_t)row * DIN);
#pragma unroll
    for (int i = 0; i < 4; ++i) {
        uint2 p;
        p.x = (unsigned)f32_to_bf16(v[i].x * inv) | ((unsigned)f32_to_bf16(v[i].y * inv) << 16);
        p.y = (unsigned)f32_to_bf16(v[i].z * inv) | ((unsigned)f32_to_bf16(v[i].w * inv) << 16);
        Ar[tid + i * 256] = p;
    }
}

// ---------------- Kernel 2: W[k][n] fp32 -> Wt[n][k] bf16, 64x64 tiles ----------------
__global__ __launch_bounds__(256) void transpose_cast_kernel(
    const float* __restrict__ W, unsigned short* __restrict__ Wt) {
    __shared__ float tile[64][65];  // +1 pad: conflict-free transposed read
    const int bn = blockIdx.x * 64, bk = blockIdx.y * 64;
    const int t = threadIdx.x;
    const int lk = t >> 4, ln4 = (t & 15) * 4;
#pragma unroll
    for (int i = 0; i < 4; ++i) {
        float4 v = *(const float4*)(W + (size_t)(bk + lk + i * 16) * NOUT + bn + ln4);
        tile[lk + i * 16][ln4 + 0] = v.x;
        tile[lk + i * 16][ln4 + 1] = v.y;
        tile[lk + i * 16][ln4 + 2] = v.z;
        tile[lk + i * 16][ln4 + 3] = v.w;
    }
    __syncthreads();
    const int ln = t >> 4, lk4 = (t & 15) * 4;
#pragma unroll
    for (int i = 0; i < 4; ++i) {
        const int n = ln + i * 16;
        uint2 p;
        p.x = (unsigned)f32_to_bf16(tile[lk4 + 0][n]) | ((unsigned)f32_to_bf16(tile[lk4 + 1][n]) << 16);
        p.y = (unsigned)f32_to_bf16(tile[lk4 + 2][n]) | ((unsigned)f32_to_bf16(tile[lk4 + 3][n]) << 16);
        *(uint2*)(Wt + (size_t)(bn + n) * DIN + bk + lk4) = p;  // 128B/row segments
    }
}

// ---------------- Kernel 3: C = relu(A @ W + b), bf16 MFMA ----------------
// A [M,K] bf16 row-major; Wt [N,K] bf16 (k contiguous); C [M,N] fp32.
// 128x128 tile, BK=32, 4 waves x (4x4) 16x16x32 MFMA tiles.
// LDS k-chunk XOR swizzle: LDS slot (row r, pos p) holds global k-chunk
// p ^ ((r>>1)&3) of row r. Permutes within each row's 64B global segment
// (coalescing preserved; global_load_lds stays lane-contiguous) and makes
// consecutive-lane ds_read_b128 groups hit all 8 bank-quads (was 2).

__device__ __forceinline__ void async_copy16(const unsigned short* g, unsigned short* l) {
    __builtin_amdgcn_global_load_lds(
        (const __attribute__((address_space(1))) unsigned int*)g,
        (__attribute__((address_space(3))) unsigned int*)l, 16, 0, 0);
}

__global__ __launch_bounds__(256, 2) void gemm_bias_relu_kernel(
    const unsigned short* __restrict__ A, const unsigned short* __restrict__ Wt,
    const float* __restrict__ bias, float* __restrict__ C) {
    __shared__ __align__(16) unsigned short As[128 * 32];
    __shared__ __align__(16) unsigned short Bs[128 * 32];
    const int tid = threadIdx.x;
    const int wave = tid >> 6, lane = tid & 63;
    const int m0 = blockIdx.y * 128, n0 = blockIdx.x * 128;
    const int wr = (wave >> 1) * 64, wc = (wave & 1) * 64;
    const int lm = lane & 15;
    const int q = lane >> 4;               // global k-chunk this lane consumes
    const int sw = (lm >> 1) & 3;          // row-dependent swizzle term
    const int ksl = (q ^ sw) * 8;          // LDS k-slot (shorts) after swizzle

    f32x4 acc[4][4] = {};

    // staging: 512 16B-chunks per matrix; LDS slot c = r*4 + p holds
    // global chunk p ^ ((r>>1)&3) = p ^ ((c>>3)&3) of row r.
    const int c0 = tid, c1 = tid + 256;
    const int p0 = ((c0 & 3) ^ ((c0 >> 3) & 3)) * 8;
    const int p1 = ((c1 & 3) ^ ((c1 >> 3) & 3)) * 8;
    const unsigned short* gA0 = A + (size_t)(m0 + (c0 >> 2)) * DIN + p0;
    const unsigned short* gA1 = A + (size_t)(m0 + (c1 >> 2)) * DIN + p1;
    const unsigned short* gB0 = Wt + (size_t)(n0 + (c0 >> 2)) * DIN + p0;
    const unsigned short* gB1 = Wt + (size_t)(n0 + (c1 >> 2)) * DIN + p1;
    // wave-uniform LDS bases (HW scatters lane i to base + i*16)
    unsigned short* lA0 = &As[(c0 & ~63) * 8];
    unsigned short* lA1 = &As[(c1 & ~63) * 8];
    unsigned short* lB0 = &Bs[(c0 & ~63) * 8];
    unsigned short* lB1 = &Bs[(c1 & ~63) * 8];

    for (int k0 = 0; k0 < DIN; k0 += 32) {
        __syncthreads();
        async_copy16(gA0 + k0, lA0);
        async_copy16(gA1 + k0, lA1);
        async_copy16(gB0 + k0, lB0);
        async_copy16(gB1 + k0, lB1);
        __syncthreads();

        short8 af[4], bf[4];
#pragma unroll
        for (int i = 0; i < 4; ++i)
            af[i] = *(const short8*)(&As[(wr + i * 16 + lm) * 32 + ksl]);
#pragma unroll
        for (int j = 0; j < 4; ++j)
            bf[j] = *(const short8*)(&Bs[(wc + j * 16 + lm) * 32 + ksl]);
#pragma unroll
        for (int i = 0; i < 4; ++i)
#pragma unroll
            for (int j = 0; j < 4; ++j)
                acc[i][j] = __builtin_amdgcn_mfma_f32_16x16x32_bf16(af[i], bf[j], acc[i][j], 0, 0, 0);
    }

    // epilogue: C/D layout col=lane&15, row=(lane>>4)*4+reg  [m89/m91]
    float bj[4];
#pragma unroll
    for (int j = 0; j < 4; ++j) bj[j] = bias[n0 + wc + j * 16 + lm];
    const int colb = n0 + wc + lm;
    const int rowb = m0 + wr + (q << 2);
#pragma unroll
    for (int i = 0; i < 4; ++i) {
#pragma unroll
        for (int r = 0; r < 4; ++r) {
            float* cp = C + (size_t)(rowb + i * 16 + r) * NOUT + colb;
#pragma unroll
            for (int j = 0; j < 4; ++j) {
                float v = acc[i][j][r] + bj[j];
                __builtin_nontemporal_store(v > 0.f ? v : 0.f, cp + j * 16);
            }
        }
    }
}

extern "C" void kernel_launch(void* const* d_in, const int* in_sizes, int n_in,
                              void* d_out, int out_size, void* d_ws, size_t ws_size,
                              hipStream_t stream) {
    const float* x = (const float*)d_in[0];
    const float* W = (const float*)d_in[1];
    const float* b = (const float*)d_in[2];
    float* out = (float*)d_out;

    // ws layout: A_bf16 [16384*4096] (128 MiB) | Wt_bf16 [4096*4096] (32 MiB)
    unsigned short* Abf = (unsigned short*)d_ws;
    unsigned short* Wt = Abf + (size_t)BROWS * DIN;

    normalize_cast_kernel<<<BROWS, 256, 0, stream>>>(x, Abf);
    transpose_cast_kernel<<<dim3(NOUT / 64, DIN / 64), 256, 0, stream>>>(W, Wt);
    gemm_bias_relu_kernel<<<dim3(NOUT / 128, BROWS / 128), 256, 0, stream>>>(Abf, Wt, b, out);
}